// Round 1
// baseline (5952.786 us; speedup 1.0000x reference)
//
#include <hip/hip_runtime.h>

#define N 256
#define NN 65536
#define EMB 64
#define BATCH 8
#define NEDGE 32768

// ---------------- adjacency scatter ----------------
__global__ void scatter_adj(const int* __restrict__ ei, const int* __restrict__ batch,
                            float* __restrict__ adj) {
    int e = blockIdx.x * blockDim.x + threadIdx.x;
    if (e >= NEDGE) return;
    int src = ei[e];           // edge_index[0][e]
    int dst = ei[NEDGE + e];   // edge_index[1][e]
    int g = batch[src];
    int lu = src - g * N;
    int lv = dst - g * N;
    atomicAdd(&adj[(size_t)g * NN + (size_t)lu * N + lv], 1.0f);
}

// ---------------- rb0 MLP path: h1 = relu(w1[:,0]*adj + b1); out = relu(W2 h1 + b2) ----------------
__global__ void mlp2_rb0(const float* __restrict__ adj,
                         const float* __restrict__ w1, const float* __restrict__ b1,
                         const float* __restrict__ w2, const float* __restrict__ b2,
                         float* __restrict__ out, int b_base) {
    int p = blockIdx.x * blockDim.x + threadIdx.x;
    int bb = blockIdx.y;
    float a = adj[(size_t)(b_base + bb) * NN + p];
    float h[EMB];
#pragma unroll
    for (int o = 0; o < EMB; ++o) {
        float v = w1[o * 2] * a + b1[o];
        h[o] = v > 0.0f ? v : 0.0f;
    }
    size_t obase = (size_t)bb * EMB * NN + p;
    for (int oc = 0; oc < EMB; oc += 16) {
        float acc[16];
#pragma unroll
        for (int i = 0; i < 16; ++i) acc[i] = b2[oc + i];
        for (int k = 0; k < EMB; ++k) {
#pragma unroll
            for (int i = 0; i < 16; ++i)
                acc[i] += w2[(oc + i) * EMB + k] * h[k];
        }
#pragma unroll
        for (int i = 0; i < 16; ++i) {
            float v = acc[i] > 0.0f ? acc[i] : 0.0f;
            out[obase + (size_t)(oc + i) * NN] = v;
        }
    }
}

// ---------------- generic MLP path (Cin=64): out = relu(W2 relu(W1 z + b1) + b2) ----------------
__global__ void mlp2(const float* __restrict__ z,
                     const float* __restrict__ w1, const float* __restrict__ b1,
                     const float* __restrict__ w2, const float* __restrict__ b2,
                     float* __restrict__ out) {
    int p = blockIdx.x * blockDim.x + threadIdx.x;
    int bb = blockIdx.y;
    size_t base = (size_t)bb * EMB * NN + p;
    float h[EMB];
#pragma unroll
    for (int o = 0; o < EMB; ++o) h[o] = b1[o];
    for (int c = 0; c < EMB; ++c) {
        float zc = z[base + (size_t)c * NN];
#pragma unroll
        for (int o = 0; o < EMB; ++o)
            h[o] += w1[o * EMB + c] * zc;
    }
#pragma unroll
    for (int o = 0; o < EMB; ++o) h[o] = h[o] > 0.0f ? h[o] : 0.0f;
    for (int oc = 0; oc < EMB; oc += 16) {
        float acc[16];
#pragma unroll
        for (int i = 0; i < 16; ++i) acc[i] = b2[oc + i];
        for (int k = 0; k < EMB; ++k) {
#pragma unroll
            for (int i = 0; i < 16; ++i)
                acc[i] += w2[(oc + i) * EMB + k] * h[k];
        }
#pragma unroll
        for (int i = 0; i < 16; ++i) {
            float v = acc[i] > 0.0f ? acc[i] : 0.0f;
            out[base + (size_t)(oc + i) * NN] = v;
        }
    }
}

// ---------------- per-channel NxN matmul: mult[b,c] = m1[b,c] @ m2[b,c] ----------------
__global__ void chanmm(const float* __restrict__ m1, const float* __restrict__ m2,
                       float* __restrict__ out) {
    __shared__ float As[32][33];
    __shared__ float Bs[32][33];
    int tid = threadIdx.x;
    int tx = tid & 15, ty = tid >> 4;
    int tile = blockIdx.x;
    int trow = (tile >> 3) * 32, tcol = (tile & 7) * 32;
    size_t base = ((size_t)blockIdx.z * EMB + blockIdx.y) * NN;
    const float* A = m1 + base;
    const float* Bm = m2 + base;
    float acc00 = 0, acc01 = 0, acc10 = 0, acc11 = 0;
    for (int k0 = 0; k0 < N; k0 += 32) {
#pragma unroll
        for (int i = 0; i < 4; ++i) {
            int idx = i * 256 + tid;
            int r = idx >> 5, c = idx & 31;
            As[r][c] = A[(size_t)(trow + r) * N + (k0 + c)];
            Bs[r][c] = Bm[(size_t)(k0 + r) * N + (tcol + c)];
        }
        __syncthreads();
#pragma unroll
        for (int k = 0; k < 32; ++k) {
            float a0 = As[ty * 2][k], a1 = As[ty * 2 + 1][k];
            float b0 = Bs[k][tx * 2], b1v = Bs[k][tx * 2 + 1];
            acc00 += a0 * b0; acc01 += a0 * b1v;
            acc10 += a1 * b0; acc11 += a1 * b1v;
        }
        __syncthreads();
    }
    float* O = out + base;
    int r = trow + ty * 2, c = tcol + tx * 2;
    O[(size_t)r * N + c] = acc00;
    O[(size_t)r * N + c + 1] = acc01;
    O[(size_t)(r + 1) * N + c] = acc10;
    O[(size_t)(r + 1) * N + c + 1] = acc11;
}

// ---------------- skip conv rb0: out[o] = sw[o,0]*adj + sum_c sw[o,2+c]*mult[c] + sb[o] ----------------
__global__ void skip_rb0(const float* __restrict__ adj, const float* __restrict__ mult,
                         const float* __restrict__ sw, const float* __restrict__ sb,
                         float* __restrict__ out, int b_base) {
    int p = blockIdx.x * blockDim.x + threadIdx.x;
    int bb = blockIdx.y;
    float a = adj[(size_t)(b_base + bb) * NN + p];
    size_t base = (size_t)bb * EMB * NN + p;
    float acc[EMB];
#pragma unroll
    for (int o = 0; o < EMB; ++o) acc[o] = sb[o] + sw[o * 66] * a;
    for (int c = 0; c < EMB; ++c) {
        float mc = mult[base + (size_t)c * NN];
#pragma unroll
        for (int o = 0; o < EMB; ++o)
            acc[o] += sw[o * 66 + 2 + c] * mc;
    }
#pragma unroll
    for (int o = 0; o < EMB; ++o) out[base + (size_t)o * NN] = acc[o];
}

// ---------------- skip conv generic: out[o] = sum_c sw[o,c]*z[c] + sw[o,64+c]*mult[c] + sb[o] ----------------
__global__ void skip_k(const float* __restrict__ z, const float* __restrict__ mult,
                       const float* __restrict__ sw, const float* __restrict__ sb,
                       float* __restrict__ out) {
    int p = blockIdx.x * blockDim.x + threadIdx.x;
    int bb = blockIdx.y;
    size_t base = (size_t)bb * EMB * NN + p;
    float acc[EMB];
#pragma unroll
    for (int o = 0; o < EMB; ++o) acc[o] = sb[o];
    for (int c = 0; c < EMB; ++c) {
        float zc = z[base + (size_t)c * NN];
        float mc = mult[base + (size_t)c * NN];
#pragma unroll
        for (int o = 0; o < EMB; ++o)
            acc[o] += sw[o * 128 + c] * zc + sw[o * 128 + 64 + c] * mc;
    }
#pragma unroll
    for (int o = 0; o < EMB; ++o) out[base + (size_t)o * NN] = acc[o];
}

// ---------------- pooling partials: sum_all / sum_diag per (b,c) ----------------
__global__ void pool(const float* __restrict__ z, float* __restrict__ sums, int b_base) {
    int bb = blockIdx.x;
    int c = blockIdx.y;
    size_t base = ((size_t)bb * EMB + c) * NN;
    float s = 0.0f, d = 0.0f;
    for (int idx = threadIdx.x; idx < NN; idx += 256) {
        float v = z[base + idx];
        s += v;
        if (idx % 257 == 0) d += v;
    }
    for (int off = 32; off > 0; off >>= 1) {
        s += __shfl_down(s, off);
        d += __shfl_down(d, off);
    }
    __shared__ float ls[4], ld[4];
    int wid = threadIdx.x >> 6;
    if ((threadIdx.x & 63) == 0) { ls[wid] = s; ld[wid] = d; }
    __syncthreads();
    if (threadIdx.x == 0) {
        s = ls[0] + ls[1] + ls[2] + ls[3];
        d = ld[0] + ld[1] + ld[2] + ld[3];
        int b = b_base + bb;
        sums[b * EMB + c] = s;
        sums[BATCH * EMB + b * EMB + c] = d;
    }
}

// ---------------- final pooled FC ----------------
__global__ void fc(const float* __restrict__ sums,
                   const float* __restrict__ fcw1, const float* __restrict__ fcb1,
                   const float* __restrict__ fcw2, const float* __restrict__ fcb2,
                   float* __restrict__ out) {
    int b = blockIdx.x;
    __shared__ float h[128];
    __shared__ float hh[64];
    int t = threadIdx.x;  // 128 threads
    if (t < 64) {
        h[t] = sums[BATCH * EMB + b * EMB + t] / (float)N;  // mean_diag
    } else {
        int c = t - 64;
        float sall = sums[b * EMB + c];
        float sd = sums[BATCH * EMB + b * EMB + c];
        h[t] = (sall - sd) / (float)(N * (N - 1));          // mean_offdiag
    }
    __syncthreads();
    if (t < 64) {
        float acc = fcb1[t];
        for (int k = 0; k < 128; ++k) acc += fcw1[t * 128 + k] * h[k];
        hh[t] = acc > 0.0f ? acc : 0.0f;
    }
    __syncthreads();
    if (t == 0) {
        float acc = fcb2[0];
        for (int k = 0; k < 64; ++k) acc += fcw2[k] * hh[k];
        out[b] = acc;
    }
}

extern "C" void kernel_launch(void* const* d_in, const int* in_sizes, int n_in,
                              void* d_out, int out_size, void* d_ws, size_t ws_size,
                              hipStream_t stream) {
    const int* ei       = (const int*)d_in[0];
    const int* batchv   = (const int*)d_in[1];
    const float* rb0_m1w1 = (const float*)d_in[2];
    const float* rb0_m1b1 = (const float*)d_in[3];
    const float* rb0_m1w2 = (const float*)d_in[4];
    const float* rb0_m1b2 = (const float*)d_in[5];
    const float* rb0_m2w1 = (const float*)d_in[6];
    const float* rb0_m2b1 = (const float*)d_in[7];
    const float* rb0_m2w2 = (const float*)d_in[8];
    const float* rb0_m2b2 = (const float*)d_in[9];
    const float* rb0_sw   = (const float*)d_in[10];
    const float* rb0_sb   = (const float*)d_in[11];
    const float* rb_m1w1  = (const float*)d_in[12];
    const float* rb_m1b1  = (const float*)d_in[13];
    const float* rb_m1w2  = (const float*)d_in[14];
    const float* rb_m1b2  = (const float*)d_in[15];
    const float* rb_m2w1  = (const float*)d_in[16];
    const float* rb_m2b1  = (const float*)d_in[17];
    const float* rb_m2w2  = (const float*)d_in[18];
    const float* rb_m2b2  = (const float*)d_in[19];
    const float* rb_sw    = (const float*)d_in[20];
    const float* rb_sb    = (const float*)d_in[21];
    const float* fcw1     = (const float*)d_in[22];
    const float* fcb1     = (const float*)d_in[23];
    const float* fcw2     = (const float*)d_in[24];
    const float* fcb2     = (const float*)d_in[25];

    float* ws = (float*)d_ws;
    float* adj  = ws;                        // B*N*N = 524288 floats
    float* sums = ws + 524288;               // 2*B*EMB = 1024 floats
    float* bufs = ws + 524288 + 1024;

    const size_t per = (size_t)EMB * NN;     // 4,194,304 floats per graph per buffer
    int g = BATCH;
    while (g > 1) {
        size_t need = (524288ull + 1024ull + 4ull * (size_t)g * per) * 4ull;
        if (need <= ws_size) break;
        g >>= 1;
    }

    float* bZ  = bufs;
    float* bM1 = bufs + (size_t)g * per;
    float* bM2 = bufs + 2ull * (size_t)g * per;
    float* bMu = bufs + 3ull * (size_t)g * per;

    hipMemsetAsync(adj, 0, 524288ull * 4ull, stream);
    scatter_adj<<<NEDGE / 256, 256, 0, stream>>>(ei, batchv, adj);

    for (int b_base = 0; b_base < BATCH; b_base += g) {
        dim3 gridP(NN / 256, g);
        dim3 gridM(64, EMB, g);
        // rb0
        mlp2_rb0<<<gridP, 256, 0, stream>>>(adj, rb0_m1w1, rb0_m1b1, rb0_m1w2, rb0_m1b2, bM1, b_base);
        mlp2_rb0<<<gridP, 256, 0, stream>>>(adj, rb0_m2w1, rb0_m2b1, rb0_m2w2, rb0_m2b2, bM2, b_base);
        chanmm<<<gridM, 256, 0, stream>>>(bM1, bM2, bMu);
        skip_rb0<<<gridP, 256, 0, stream>>>(adj, bMu, rb0_sw, rb0_sb, bZ, b_base);

        float* pz = bZ; float* pm1 = bM1; float* pm2 = bM2; float* pmu = bMu;
        for (int i = 0; i < 3; ++i) {
            mlp2<<<gridP, 256, 0, stream>>>(pz, rb_m1w1 + (size_t)i * 4096, rb_m1b1 + i * 64,
                                            rb_m1w2 + (size_t)i * 4096, rb_m1b2 + i * 64, pm1);
            mlp2<<<gridP, 256, 0, stream>>>(pz, rb_m2w1 + (size_t)i * 4096, rb_m2b1 + i * 64,
                                            rb_m2w2 + (size_t)i * 4096, rb_m2b2 + i * 64, pm2);
            chanmm<<<gridM, 256, 0, stream>>>(pm1, pm2, pmu);
            skip_k<<<gridP, 256, 0, stream>>>(pz, pmu, rb_sw + (size_t)i * 8192, rb_sb + i * 64, pm1);
            float* t = pz; pz = pm1; pm1 = t;
        }
        pool<<<dim3(g, EMB), 256, 0, stream>>>(pz, sums, b_base);
    }
    fc<<<BATCH, 128, 0, stream>>>(sums, fcw1, fcb1, fcw2, fcb2, (float*)d_out);
}

// Round 5
// 2729.181 us; speedup vs baseline: 2.1812x; 2.1812x over previous
//
#include <hip/hip_runtime.h>

#define N 256
#define NN 65536
#define EMB 64
#define BATCH 8
#define NEDGE 32768

typedef unsigned short u16;
typedef unsigned int u32t;
typedef __attribute__((ext_vector_type(8))) short bf16x8;
typedef __attribute__((ext_vector_type(4))) float f32x4;

#define TSTR 72    // act/weight-64 LDS tile row stride in u16 (144 B -> 2-way bank alias only)
#define WSTR2 136  // K=128 weight tile row stride in u16 (272 B -> 2-way)

static __device__ __forceinline__ u16 f2bs(float f) {
    u32t u = __float_as_uint(f);
    u32t r = (u + 0x7FFFu + ((u >> 16) & 1u)) >> 16;
    return (u16)r;
}
static __device__ __forceinline__ float b2f(u16 s) {
    return __uint_as_float(((u32t)s) << 16);
}
// split fp32 into bf16 hi + bf16 lo (a ~= hi + lo, residual ~2^-16 * a)
static __device__ __forceinline__ void split_bf(float a, u16& hi, u16& lo) {
    hi = f2bs(a);
    float r = a - b2f(hi);
    lo = f2bs(r);
}

// ---------------- adjacency scatter ----------------
__global__ void scatter_adj(const int* __restrict__ ei, const int* __restrict__ batch,
                            float* __restrict__ adj) {
    int e = blockIdx.x * blockDim.x + threadIdx.x;
    if (e >= NEDGE) return;
    int src = ei[e];
    int dst = ei[NEDGE + e];
    int g = batch[src];
    int lu = src - g * N;
    int lv = dst - g * N;
    atomicAdd(&adj[(size_t)g * NN + (size_t)lu * N + lv], 1.0f);
}

// ================= split-MFMA engine helpers =================

// stage 64x64 fp32 weights (row-major, row stride ldw, col offset cofs) -> hi/lo LDS tiles
__device__ __forceinline__ void stage_w(const float* __restrict__ W, int ldw, int cofs,
                                        u16* wh, u16* wl, int t) {
#pragma unroll
    for (int it = 0; it < 8; ++it) {
        int idx = it * 256 + t;
        int o = idx >> 5;
        int c0 = (idx & 31) * 2;
        float v0 = W[o * ldw + cofs + c0];
        float v1 = W[o * ldw + cofs + c0 + 1];
        u16 h0, l0, h1, l1;
        split_bf(v0, h0, l0); split_bf(v1, h1, l1);
        *(u32t*)&wh[o * TSTR + c0] = (u32t)h0 | ((u32t)h1 << 16);
        *(u32t*)&wl[o * TSTR + c0] = (u32t)l0 | ((u32t)l1 << 16);
    }
}

// stage 64x128 fp32 weights -> hi/lo LDS tiles (stride WSTR2)
__device__ __forceinline__ void stage_w128(const float* __restrict__ W,
                                           u16* wh, u16* wl, int t) {
#pragma unroll
    for (int it = 0; it < 16; ++it) {
        int idx = it * 256 + t;
        int o = idx >> 6;
        int c0 = (idx & 63) * 2;
        float v0 = W[o * 128 + c0];
        float v1 = W[o * 128 + c0 + 1];
        u16 h0, l0, h1, l1;
        split_bf(v0, h0, l0); split_bf(v1, h1, l1);
        *(u32t*)&wh[o * WSTR2 + c0] = (u32t)h0 | ((u32t)h1 << 16);
        *(u32t*)&wl[o * WSTR2 + c0] = (u32t)l0 | ((u32t)l1 << 16);
    }
}

// stage 64px x 64c activation tile from NCHW fp32 (plane stride NN) -> [px][c] hi/lo
__device__ __forceinline__ void stage_act_nchw(const float* __restrict__ src, int p0,
                                               u16* ah, u16* al, int t) {
#pragma unroll
    for (int it = 0; it < 8; ++it) {
        int idx = it * 256 + t;
        int px = idx & 63;
        int c0 = (idx >> 6) * 2;
        float v0 = src[(size_t)c0 * NN + p0 + px];
        float v1 = src[(size_t)(c0 + 1) * NN + p0 + px];
        u16 h0, l0, h1, l1;
        split_bf(v0, h0, l0); split_bf(v1, h1, l1);
        *(u32t*)&ah[px * TSTR + c0] = (u32t)h0 | ((u32t)h1 << 16);
        *(u32t*)&al[px * TSTR + c0] = (u32t)l0 | ((u32t)l1 << 16);
    }
}

// stage 64px x 64c activation tile from NHWC fp32 -> [px][c] hi/lo
__device__ __forceinline__ void stage_act_nhwc(const float* __restrict__ src, int p0,
                                               u16* ah, u16* al, int t) {
#pragma unroll
    for (int it = 0; it < 4; ++it) {
        int idx = it * 256 + t;
        int px = idx >> 4;
        int cq = (idx & 15) * 4;
        const float4 v = *(const float4*)&src[(size_t)(p0 + px) * EMB + cq];
        u16 h0, l0, h1, l1, h2, l2, h3, l3;
        split_bf(v.x, h0, l0); split_bf(v.y, h1, l1);
        split_bf(v.z, h2, l2); split_bf(v.w, h3, l3);
        *(u32t*)&ah[px * TSTR + cq]     = (u32t)h0 | ((u32t)h1 << 16);
        *(u32t*)&ah[px * TSTR + cq + 2] = (u32t)h2 | ((u32t)h3 << 16);
        *(u32t*)&al[px * TSTR + cq]     = (u32t)l0 | ((u32t)l1 << 16);
        *(u32t*)&al[px * TSTR + cq + 2] = (u32t)l2 | ((u32t)l3 << 16);
    }
}

__device__ __forceinline__ void init_bias(const float* __restrict__ Bb, f32x4* acc, int lane) {
    int q = lane >> 4;
#pragma unroll
    for (int ot = 0; ot < 4; ++ot)
#pragma unroll
        for (int j = 0; j < 4; ++j)
            acc[ot][j] = Bb[ot * 16 + q * 4 + j];
}

// one K=64 GEMM pass with 3-term split MFMA: acc[ot] += W[64 o][64 k] * act^T[k][px]
__device__ __forceinline__ void layer_half(const u16* bh, const u16* bl,
                                           const u16* wh, const u16* wl,
                                           int wstr, int ak0,
                                           f32x4* acc, int wv, int lane) {
    int q = lane >> 4, l = lane & 15;
#pragma unroll
    for (int ks = 0; ks < 2; ++ks) {
        int boff = (wv * 16 + l) * TSTR + ks * 32 + q * 8;
        bf16x8 bhi = *(const bf16x8*)&bh[boff];
        bf16x8 blo = *(const bf16x8*)&bl[boff];
#pragma unroll
        for (int ot = 0; ot < 4; ++ot) {
            int aoff = (ot * 16 + l) * wstr + ak0 + ks * 32 + q * 8;
            bf16x8 ahi = *(const bf16x8*)&wh[aoff];
            bf16x8 alo = *(const bf16x8*)&wl[aoff];
            acc[ot] = __builtin_amdgcn_mfma_f32_16x16x32_bf16(ahi, bhi, acc[ot], 0, 0, 0);
            acc[ot] = __builtin_amdgcn_mfma_f32_16x16x32_bf16(ahi, blo, acc[ot], 0, 0, 0);
            acc[ot] = __builtin_amdgcn_mfma_f32_16x16x32_bf16(alo, bhi, acc[ot], 0, 0, 0);
        }
    }
}

// write h = relu(acc) split into hi/lo LDS tiles at [px][o] (wave-local rows)
__device__ __forceinline__ void write_h(f32x4* acc, u16* hh, u16* hl, int wv, int lane) {
    int q = lane >> 4, l = lane & 15;
    int px = wv * 16 + l;
#pragma unroll
    for (int ot = 0; ot < 4; ++ot) {
#pragma unroll
        for (int jp = 0; jp < 2; ++jp) {
            int o = ot * 16 + q * 4 + jp * 2;
            float v0 = acc[ot][jp * 2];     v0 = v0 > 0.f ? v0 : 0.f;
            float v1 = acc[ot][jp * 2 + 1]; v1 = v1 > 0.f ? v1 : 0.f;
            u16 h0, l0, h1, l1;
            split_bf(v0, h0, l0); split_bf(v1, h1, l1);
            *(u32t*)&hh[px * TSTR + o] = (u32t)h0 | ((u32t)h1 << 16);
            *(u32t*)&hl[px * TSTR + o] = (u32t)l0 | ((u32t)l1 << 16);
        }
    }
}

// write relu(acc) to fp32 NCHW plane set (base pre-offset by graph)
__device__ __forceinline__ void write_m_relu(f32x4* acc, float* __restrict__ mout,
                                             int p0, int wv, int lane) {
    int q = lane >> 4, l = lane & 15;
    int px = p0 + wv * 16 + l;
#pragma unroll
    for (int ot = 0; ot < 4; ++ot)
#pragma unroll
        for (int j = 0; j < 4; ++j) {
            int o = ot * 16 + q * 4 + j;
            float v = acc[ot][j]; v = v > 0.f ? v : 0.f;
            mout[(size_t)o * NN + px] = v;
        }
}

// write acc (no relu) to fp32 NCHW
__device__ __forceinline__ void write_m_lin(f32x4* acc, float* __restrict__ mout,
                                            int p0, int wv, int lane) {
    int q = lane >> 4, l = lane & 15;
    int px = p0 + wv * 16 + l;
#pragma unroll
    for (int ot = 0; ot < 4; ++ot)
#pragma unroll
        for (int j = 0; j < 4; ++j) {
            int o = ot * 16 + q * 4 + j;
            mout[(size_t)o * NN + px] = acc[ot][j];
        }
}

// ---------------- f1 regular: z(NCHW fp32) -> m1,m2 (NCHW fp32), both MLP branches ----------------
__global__ __launch_bounds__(256) void f1_reg(
    const float* __restrict__ z,
    const float* __restrict__ W1a, const float* __restrict__ B1a,
    const float* __restrict__ W2a, const float* __restrict__ B2a,
    const float* __restrict__ W1b, const float* __restrict__ B1b,
    const float* __restrict__ W2b, const float* __restrict__ B2b,
    float* __restrict__ m1, float* __restrict__ m2) {
    __shared__ u16 zh[64 * TSTR], zl[64 * TSTR];
    __shared__ u16 hh[64 * TSTR], hl[64 * TSTR];
    __shared__ u16 wh[64 * TSTR], wl[64 * TSTR];
    int bb = blockIdx.y, p0 = blockIdx.x * 64;
    int t = threadIdx.x, lane = t & 63, wv = t >> 6;
    const float* zp = z + (size_t)bb * EMB * NN;
    float* m1p = m1 + (size_t)bb * EMB * NN;
    float* m2p = m2 + (size_t)bb * EMB * NN;

    stage_act_nchw(zp, p0, zh, zl, t);
    stage_w(W1a, 64, 0, wh, wl, t);
    __syncthreads();

    f32x4 acc[4];
    init_bias(B1a, acc, lane);
    layer_half(zh, zl, wh, wl, TSTR, 0, acc, wv, lane);
    write_h(acc, hh, hl, wv, lane);
    __syncthreads();

    stage_w(W2a, 64, 0, wh, wl, t);
    __syncthreads();
    init_bias(B2a, acc, lane);
    layer_half(hh, hl, wh, wl, TSTR, 0, acc, wv, lane);
    write_m_relu(acc, m1p, p0, wv, lane);
    __syncthreads();

    stage_w(W1b, 64, 0, wh, wl, t);
    __syncthreads();
    init_bias(B1b, acc, lane);
    layer_half(zh, zl, wh, wl, TSTR, 0, acc, wv, lane);
    write_h(acc, hh, hl, wv, lane);
    __syncthreads();

    stage_w(W2b, 64, 0, wh, wl, t);
    __syncthreads();
    init_bias(B2b, acc, lane);
    layer_half(hh, hl, wh, wl, TSTR, 0, acc, wv, lane);
    write_m_relu(acc, m2p, p0, wv, lane);
}

// ---------------- f1 rb0: adj -> m1,m2 (layer1 is rank-1 in fp32, layer2 split-MFMA) ----------------
__global__ __launch_bounds__(256) void f1_rb0(
    const float* __restrict__ adj, int b_base,
    const float* __restrict__ w1a, const float* __restrict__ b1a,
    const float* __restrict__ W2a, const float* __restrict__ B2a,
    const float* __restrict__ w1b, const float* __restrict__ b1b,
    const float* __restrict__ W2b, const float* __restrict__ B2b,
    float* __restrict__ m1, float* __restrict__ m2) {
    __shared__ u16 hh[64 * TSTR], hl[64 * TSTR];
    __shared__ u16 wh[64 * TSTR], wl[64 * TSTR];
    int bb = blockIdx.y, p0 = blockIdx.x * 64;
    int t = threadIdx.x, lane = t & 63, wv = t >> 6;
    float* m1p = m1 + (size_t)bb * EMB * NN;
    float* m2p = m2 + (size_t)bb * EMB * NN;

    int px = t & 63, oc = (t >> 6) * 16;
    float a = adj[(size_t)(b_base + bb) * NN + p0 + px];

#pragma unroll
    for (int k = 0; k < 16; k += 2) {
        int o = oc + k;
        float v0 = w1a[o * 2] * a + b1a[o];           v0 = v0 > 0.f ? v0 : 0.f;
        float v1 = w1a[(o + 1) * 2] * a + b1a[o + 1]; v1 = v1 > 0.f ? v1 : 0.f;
        u16 h0, l0, h1, l1; split_bf(v0, h0, l0); split_bf(v1, h1, l1);
        *(u32t*)&hh[px * TSTR + o] = (u32t)h0 | ((u32t)h1 << 16);
        *(u32t*)&hl[px * TSTR + o] = (u32t)l0 | ((u32t)l1 << 16);
    }
    stage_w(W2a, 64, 0, wh, wl, t);
    __syncthreads();

    f32x4 acc[4];
    init_bias(B2a, acc, lane);
    layer_half(hh, hl, wh, wl, TSTR, 0, acc, wv, lane);
    write_m_relu(acc, m1p, p0, wv, lane);
    __syncthreads();

#pragma unroll
    for (int k = 0; k < 16; k += 2) {
        int o = oc + k;
        float v0 = w1b[o * 2] * a + b1b[o];           v0 = v0 > 0.f ? v0 : 0.f;
        float v1 = w1b[(o + 1) * 2] * a + b1b[o + 1]; v1 = v1 > 0.f ? v1 : 0.f;
        u16 h0, l0, h1, l1; split_bf(v0, h0, l0); split_bf(v1, h1, l1);
        *(u32t*)&hh[px * TSTR + o] = (u32t)h0 | ((u32t)h1 << 16);
        *(u32t*)&hl[px * TSTR + o] = (u32t)l0 | ((u32t)l1 << 16);
    }
    stage_w(W2b, 64, 0, wh, wl, t);
    __syncthreads();

    init_bias(B2b, acc, lane);
    layer_half(hh, hl, wh, wl, TSTR, 0, acc, wv, lane);
    write_m_relu(acc, m2p, p0, wv, lane);
}

// ---------------- per-channel NxN matmul, fp32 vector, 64x64 tile / 4x4 per thread ----------------
// out written NHWC fp32 (so f2 can stage it with float4 loads)
__global__ __launch_bounds__(256) void chanmm(const float* __restrict__ m1,
                                              const float* __restrict__ m2,
                                              float* __restrict__ outNHWC) {
    __shared__ float As[64][33];
    __shared__ float Bs[32][65];
    int t = threadIdx.x;
    int tx = t & 15, ty = t >> 4;
    int tile = blockIdx.x;
    int trow = (tile >> 2) * 64, tcol = (tile & 3) * 64;
    int ch = blockIdx.y, bb = blockIdx.z;
    const float* A = m1 + ((size_t)bb * EMB + ch) * NN;
    const float* B = m2 + ((size_t)bb * EMB + ch) * NN;
    float acc[4][4] = {};
    for (int k0 = 0; k0 < N; k0 += 32) {
#pragma unroll
        for (int i = 0; i < 8; ++i) {
            int idx = i * 256 + t;
            int r = idx >> 5, c = idx & 31;
            As[r][c] = A[(size_t)(trow + r) * N + k0 + c];
        }
#pragma unroll
        for (int i = 0; i < 8; ++i) {
            int idx = i * 256 + t;
            int r = idx >> 6, c = idx & 63;
            Bs[r][c] = B[(size_t)(k0 + r) * N + tcol + c];
        }
        __syncthreads();
#pragma unroll
        for (int k = 0; k < 32; ++k) {
            float a0 = As[ty * 4 + 0][k], a1 = As[ty * 4 + 1][k];
            float a2 = As[ty * 4 + 2][k], a3 = As[ty * 4 + 3][k];
            float4 bv = *(const float4*)&Bs[k][tx * 4];
            acc[0][0] += a0 * bv.x; acc[0][1] += a0 * bv.y; acc[0][2] += a0 * bv.z; acc[0][3] += a0 * bv.w;
            acc[1][0] += a1 * bv.x; acc[1][1] += a1 * bv.y; acc[1][2] += a1 * bv.z; acc[1][3] += a1 * bv.w;
            acc[2][0] += a2 * bv.x; acc[2][1] += a2 * bv.y; acc[2][2] += a2 * bv.z; acc[2][3] += a2 * bv.w;
            acc[3][0] += a3 * bv.x; acc[3][1] += a3 * bv.y; acc[3][2] += a3 * bv.z; acc[3][3] += a3 * bv.w;
        }
        __syncthreads();
    }
#pragma unroll
    for (int i = 0; i < 4; ++i)
#pragma unroll
        for (int j = 0; j < 4; ++j) {
            int r = trow + ty * 4 + i, c = tcol + tx * 4 + j;
            outNHWC[((size_t)bb * NN + (size_t)r * N + c) * EMB + ch] = acc[i][j];
        }
}

// ---------------- f2 regular: skip conv, K=128 GEMM over [z || mult] -> z (in-place NCHW) ----------------
__global__ __launch_bounds__(256) void f2_reg(
    const float* __restrict__ mult,  // NHWC fp32
    const float* __restrict__ SW, const float* __restrict__ SB,  // [64][128], [64]
    float* __restrict__ z) {         // NCHW fp32, read+write
    __shared__ u16 ah[64 * TSTR], al[64 * TSTR];
    __shared__ u16 wh[64 * WSTR2], wl[64 * WSTR2];
    int bb = blockIdx.y, p0 = blockIdx.x * 64;
    int t = threadIdx.x, lane = t & 63, wv = t >> 6;
    const float* mp = mult + (size_t)bb * NN * EMB;
    float* zp = z + (size_t)bb * EMB * NN;

    stage_w128(SW, wh, wl, t);
    stage_act_nchw(zp, p0, ah, al, t);
    __syncthreads();

    f32x4 acc[4];
    init_bias(SB, acc, lane);
    layer_half(ah, al, wh, wl, WSTR2, 0, acc, wv, lane);   // z half (k 0..63)
    __syncthreads();
    stage_act_nhwc(mp, p0, ah, al, t);
    __syncthreads();
    layer_half(ah, al, wh, wl, WSTR2, 64, acc, wv, lane);  // mult half (k 64..127)
    write_m_lin(acc, zp, p0, wv, lane);
}

// ---------------- f2 rb0: skip conv, K=64 (mult) + rank-1 adj term -> z ----------------
__global__ __launch_bounds__(256) void f2_rb0(
    const float* __restrict__ adj, int b_base,
    const float* __restrict__ mult,  // NHWC fp32
    const float* __restrict__ SW, const float* __restrict__ SB,  // [64][66], [64]
    float* __restrict__ z) {
    __shared__ u16 ah[64 * TSTR], al[64 * TSTR];
    __shared__ u16 wh[64 * TSTR], wl[64 * TSTR];
    int bb = blockIdx.y, p0 = blockIdx.x * 64;
    int t = threadIdx.x, lane = t & 63, wv = t >> 6;
    const float* mp = mult + (size_t)bb * NN * EMB;
    float* zp = z + (size_t)bb * EMB * NN;

    stage_w(SW, 66, 2, wh, wl, t);  // mult weights = sw[:, 2:66]
    stage_act_nhwc(mp, p0, ah, al, t);
    __syncthreads();

    int q = lane >> 4, l = lane & 15;
    float a = adj[(size_t)(b_base + bb) * NN + p0 + wv * 16 + l];
    f32x4 acc[4];
#pragma unroll
    for (int ot = 0; ot < 4; ++ot)
#pragma unroll
        for (int j = 0; j < 4; ++j) {
            int o = ot * 16 + q * 4 + j;
            acc[ot][j] = SB[o] + SW[o * 66] * a;  // bias + adj-channel term
        }
    layer_half(ah, al, wh, wl, TSTR, 0, acc, wv, lane);
    write_m_lin(acc, zp, p0, wv, lane);
}

// ---------------- pooling partials from NCHW fp32 ----------------
__global__ void pool(const float* __restrict__ z, float* __restrict__ sums, int b_base) {
    int bb = blockIdx.x;
    int c = blockIdx.y;
    size_t base = ((size_t)bb * EMB + c) * NN;
    float s = 0.0f, d = 0.0f;
    for (int idx = threadIdx.x; idx < NN; idx += 256) {
        float v = z[base + idx];
        s += v;
        if (idx % 257 == 0) d += v;
    }
    for (int off = 32; off > 0; off >>= 1) {
        s += __shfl_down(s, off);
        d += __shfl_down(d, off);
    }
    __shared__ float ls[4], ld[4];
    int wid = threadIdx.x >> 6;
    if ((threadIdx.x & 63) == 0) { ls[wid] = s; ld[wid] = d; }
    __syncthreads();
    if (threadIdx.x == 0) {
        s = ls[0] + ls[1] + ls[2] + ls[3];
        d = ld[0] + ld[1] + ld[2] + ld[3];
        int b = b_base + bb;
        sums[b * EMB + c] = s;
        sums[BATCH * EMB + b * EMB + c] = d;
    }
}

// ---------------- final pooled FC ----------------
__global__ void fc(const float* __restrict__ sums,
                   const float* __restrict__ fcw1, const float* __restrict__ fcb1,
                   const float* __restrict__ fcw2, const float* __restrict__ fcb2,
                   float* __restrict__ out) {
    int b = blockIdx.x;
    __shared__ float h[128];
    __shared__ float hh2[64];
    int t = threadIdx.x;  // 128 threads
    if (t < 64) {
        h[t] = sums[BATCH * EMB + b * EMB + t] / (float)N;
    } else {
        int c = t - 64;
        float sall = sums[b * EMB + c];
        float sd = sums[BATCH * EMB + b * EMB + c];
        h[t] = (sall - sd) / (float)(N * (N - 1));
    }
    __syncthreads();
    if (t < 64) {
        float acc = fcb1[t];
        for (int k = 0; k < 128; ++k) acc += fcw1[t * 128 + k] * h[k];
        hh2[t] = acc > 0.0f ? acc : 0.0f;
    }
    __syncthreads();
    if (t == 0) {
        float acc = fcb2[0];
        for (int k = 0; k < 64; ++k) acc += fcw2[k] * hh2[k];
        out[b] = acc;
    }
}

extern "C" void kernel_launch(void* const* d_in, const int* in_sizes, int n_in,
                              void* d_out, int out_size, void* d_ws, size_t ws_size,
                              hipStream_t stream) {
    const int* ei       = (const int*)d_in[0];
    const int* batchv   = (const int*)d_in[1];
    const float* rb0_m1w1 = (const float*)d_in[2];
    const float* rb0_m1b1 = (const float*)d_in[3];
    const float* rb0_m1w2 = (const float*)d_in[4];
    const float* rb0_m1b2 = (const float*)d_in[5];
    const float* rb0_m2w1 = (const float*)d_in[6];
    const float* rb0_m2b1 = (const float*)d_in[7];
    const float* rb0_m2w2 = (const float*)d_in[8];
    const float* rb0_m2b2 = (const float*)d_in[9];
    const float* rb0_sw   = (const float*)d_in[10];
    const float* rb0_sb   = (const float*)d_in[11];
    const float* rb_m1w1  = (const float*)d_in[12];
    const float* rb_m1b1  = (const float*)d_in[13];
    const float* rb_m1w2  = (const float*)d_in[14];
    const float* rb_m1b2  = (const float*)d_in[15];
    const float* rb_m2w1  = (const float*)d_in[16];
    const float* rb_m2b1  = (const float*)d_in[17];
    const float* rb_m2w2  = (const float*)d_in[18];
    const float* rb_m2b2  = (const float*)d_in[19];
    const float* rb_sw    = (const float*)d_in[20];
    const float* rb_sb    = (const float*)d_in[21];
    const float* fcw1     = (const float*)d_in[22];
    const float* fcb1     = (const float*)d_in[23];
    const float* fcw2     = (const float*)d_in[24];
    const float* fcb2     = (const float*)d_in[25];

    // adaptive graphs-per-pass; footprint at g=2 identical to round-1's proven fit (136.3 MB)
    const size_t P = (size_t)EMB * NN;               // 4,194,304 elems
    const size_t perGraphBytes = 4ull * P * 4ull;    // m1, m2, mult, znchw (all fp32)
    int g = BATCH;
    while (g > 1) {
        size_t need = 524288ull * 4ull + 4096ull + (size_t)g * perGraphBytes;
        if (need <= ws_size) break;
        g >>= 1;
    }

    char* w = (char*)d_ws;
    float* adj   = (float*)w;  w += 524288ull * 4ull;   // [B][N][N]
    float* sums  = (float*)w;  w += 4096;               // [2][B][EMB]
    float* m1    = (float*)w;  w += (size_t)g * P * 4ull;   // NCHW
    float* m2    = (float*)w;  w += (size_t)g * P * 4ull;   // NCHW
    float* mult  = (float*)w;  w += (size_t)g * P * 4ull;   // NHWC
    float* znchw = (float*)w;  w += (size_t)g * P * 4ull;   // NCHW

    hipMemsetAsync(adj, 0, 524288ull * 4ull, stream);
    scatter_adj<<<NEDGE / 256, 256, 0, stream>>>(ei, batchv, adj);

    for (int b_base = 0; b_base < BATCH; b_base += g) {
        dim3 gridE(NN / 64, g);
        dim3 gridM(16, EMB, g);

        // rb0
        f1_rb0<<<gridE, 256, 0, stream>>>(adj, b_base,
            rb0_m1w1, rb0_m1b1, rb0_m1w2, rb0_m1b2,
            rb0_m2w1, rb0_m2b1, rb0_m2w2, rb0_m2b2, m1, m2);
        chanmm<<<gridM, 256, 0, stream>>>(m1, m2, mult);
        f2_rb0<<<gridE, 256, 0, stream>>>(adj, b_base, mult, rb0_sw, rb0_sb, znchw);

        // 3 regular blocks
        for (int i = 0; i < 3; ++i) {
            f1_reg<<<gridE, 256, 0, stream>>>(znchw,
                rb_m1w1 + (size_t)i * 4096, rb_m1b1 + i * 64,
                rb_m1w2 + (size_t)i * 4096, rb_m1b2 + i * 64,
                rb_m2w1 + (size_t)i * 4096, rb_m2b1 + i * 64,
                rb_m2w2 + (size_t)i * 4096, rb_m2b2 + i * 64, m1, m2);
            chanmm<<<gridM, 256, 0, stream>>>(m1, m2, mult);
            f2_reg<<<gridE, 256, 0, stream>>>(mult, rb_sw + (size_t)i * 8192, rb_sb + i * 64, znchw);
        }

        pool<<<dim3(g, EMB), 256, 0, stream>>>(znchw, sums, b_base);
    }
    fc<<<BATCH, 128, 0, stream>>>(sums, fcw1, fcb1, fcw2, fcb2, (float*)d_out);
}

// Round 6
// 1879.349 us; speedup vs baseline: 3.1675x; 1.4522x over previous
//
#include <hip/hip_runtime.h>

#define N 256
#define NN 65536
#define EMB 64
#define BATCH 8
#define NEDGE 32768

typedef unsigned short u16;
typedef unsigned int u32t;
typedef __attribute__((ext_vector_type(8))) short bf16x8;
typedef __attribute__((ext_vector_type(4))) float f32x4;

#define TSTR 72    // LDS tile row stride in u16 (144 B)
#define WSTR2 136  // K=128 weight tile row stride in u16 (272 B)

static __device__ __forceinline__ u16 f2bs(float f) {
    u32t u = __float_as_uint(f);
    u32t r = (u + 0x7FFFu + ((u >> 16) & 1u)) >> 16;
    return (u16)r;
}
static __device__ __forceinline__ float b2f(u16 s) {
    return __uint_as_float(((u32t)s) << 16);
}
// split fp32 into bf16 hi + bf16 lo (a ~= hi + lo)
static __device__ __forceinline__ void split_bf(float a, u16& hi, u16& lo) {
    hi = f2bs(a);
    float r = a - b2f(hi);
    lo = f2bs(r);
}

// ---------------- adjacency scatter ----------------
__global__ void scatter_adj(const int* __restrict__ ei, const int* __restrict__ batch,
                            float* __restrict__ adj) {
    int e = blockIdx.x * blockDim.x + threadIdx.x;
    if (e >= NEDGE) return;
    int src = ei[e];
    int dst = ei[NEDGE + e];
    int g = batch[src];
    int lu = src - g * N;
    int lv = dst - g * N;
    atomicAdd(&adj[(size_t)g * NN + (size_t)lu * N + lv], 1.0f);
}

// ================= split-MFMA engine helpers =================

__device__ __forceinline__ void stage_w(const float* __restrict__ W, int ldw, int cofs,
                                        u16* wh, u16* wl, int t) {
#pragma unroll
    for (int it = 0; it < 8; ++it) {
        int idx = it * 256 + t;
        int o = idx >> 5;
        int c0 = (idx & 31) * 2;
        float v0 = W[o * ldw + cofs + c0];
        float v1 = W[o * ldw + cofs + c0 + 1];
        u16 h0, l0, h1, l1;
        split_bf(v0, h0, l0); split_bf(v1, h1, l1);
        *(u32t*)&wh[o * TSTR + c0] = (u32t)h0 | ((u32t)h1 << 16);
        *(u32t*)&wl[o * TSTR + c0] = (u32t)l0 | ((u32t)l1 << 16);
    }
}

__device__ __forceinline__ void stage_w128(const float* __restrict__ W,
                                           u16* wh, u16* wl, int t) {
#pragma unroll
    for (int it = 0; it < 16; ++it) {
        int idx = it * 256 + t;
        int o = idx >> 6;
        int c0 = (idx & 63) * 2;
        float v0 = W[o * 128 + c0];
        float v1 = W[o * 128 + c0 + 1];
        u16 h0, l0, h1, l1;
        split_bf(v0, h0, l0); split_bf(v1, h1, l1);
        *(u32t*)&wh[o * WSTR2 + c0] = (u32t)h0 | ((u32t)h1 << 16);
        *(u32t*)&wl[o * WSTR2 + c0] = (u32t)l0 | ((u32t)l1 << 16);
    }
}

__device__ __forceinline__ void stage_act_nchw(const float* __restrict__ src, int p0,
                                               u16* ah, u16* al, int t) {
#pragma unroll
    for (int it = 0; it < 8; ++it) {
        int idx = it * 256 + t;
        int px = idx & 63;
        int c0 = (idx >> 6) * 2;
        float v0 = src[(size_t)c0 * NN + p0 + px];
        float v1 = src[(size_t)(c0 + 1) * NN + p0 + px];
        u16 h0, l0, h1, l1;
        split_bf(v0, h0, l0); split_bf(v1, h1, l1);
        *(u32t*)&ah[px * TSTR + c0] = (u32t)h0 | ((u32t)h1 << 16);
        *(u32t*)&al[px * TSTR + c0] = (u32t)l0 | ((u32t)l1 << 16);
    }
}

__device__ __forceinline__ void stage_act_nhwc(const float* __restrict__ src, int p0,
                                               u16* ah, u16* al, int t) {
#pragma unroll
    for (int it = 0; it < 4; ++it) {
        int idx = it * 256 + t;
        int px = idx >> 4;
        int cq = (idx & 15) * 4;
        const float4 v = *(const float4*)&src[(size_t)(p0 + px) * EMB + cq];
        u16 h0, l0, h1, l1, h2, l2, h3, l3;
        split_bf(v.x, h0, l0); split_bf(v.y, h1, l1);
        split_bf(v.z, h2, l2); split_bf(v.w, h3, l3);
        *(u32t*)&ah[px * TSTR + cq]     = (u32t)h0 | ((u32t)h1 << 16);
        *(u32t*)&ah[px * TSTR + cq + 2] = (u32t)h2 | ((u32t)h3 << 16);
        *(u32t*)&al[px * TSTR + cq]     = (u32t)l0 | ((u32t)l1 << 16);
        *(u32t*)&al[px * TSTR + cq + 2] = (u32t)l2 | ((u32t)l3 << 16);
    }
}

__device__ __forceinline__ void init_bias(const float* __restrict__ Bb, f32x4* acc, int lane) {
    int q = lane >> 4;
#pragma unroll
    for (int ot = 0; ot < 4; ++ot)
#pragma unroll
        for (int j = 0; j < 4; ++j)
            acc[ot][j] = Bb[ot * 16 + q * 4 + j];
}

__device__ __forceinline__ void layer_half(const u16* bh, const u16* bl,
                                           const u16* wh, const u16* wl,
                                           int wstr, int ak0,
                                           f32x4* acc, int wv, int lane) {
    int q = lane >> 4, l = lane & 15;
#pragma unroll
    for (int ks = 0; ks < 2; ++ks) {
        int boff = (wv * 16 + l) * TSTR + ks * 32 + q * 8;
        bf16x8 bhi = *(const bf16x8*)&bh[boff];
        bf16x8 blo = *(const bf16x8*)&bl[boff];
#pragma unroll
        for (int ot = 0; ot < 4; ++ot) {
            int aoff = (ot * 16 + l) * wstr + ak0 + ks * 32 + q * 8;
            bf16x8 ahi = *(const bf16x8*)&wh[aoff];
            bf16x8 alo = *(const bf16x8*)&wl[aoff];
            acc[ot] = __builtin_amdgcn_mfma_f32_16x16x32_bf16(ahi, bhi, acc[ot], 0, 0, 0);
            acc[ot] = __builtin_amdgcn_mfma_f32_16x16x32_bf16(ahi, blo, acc[ot], 0, 0, 0);
            acc[ot] = __builtin_amdgcn_mfma_f32_16x16x32_bf16(alo, bhi, acc[ot], 0, 0, 0);
        }
    }
}

__device__ __forceinline__ void write_h(f32x4* acc, u16* hh, u16* hl, int wv, int lane) {
    int q = lane >> 4, l = lane & 15;
    int px = wv * 16 + l;
#pragma unroll
    for (int ot = 0; ot < 4; ++ot) {
#pragma unroll
        for (int jp = 0; jp < 2; ++jp) {
            int o = ot * 16 + q * 4 + jp * 2;
            float v0 = acc[ot][jp * 2];     v0 = v0 > 0.f ? v0 : 0.f;
            float v1 = acc[ot][jp * 2 + 1]; v1 = v1 > 0.f ? v1 : 0.f;
            u16 h0, l0, h1, l1;
            split_bf(v0, h0, l0); split_bf(v1, h1, l1);
            *(u32t*)&hh[px * TSTR + o] = (u32t)h0 | ((u32t)h1 << 16);
            *(u32t*)&hl[px * TSTR + o] = (u32t)l0 | ((u32t)l1 << 16);
        }
    }
}

// write relu(acc) pre-split to hi/lo u16 NCHW planes (chanmm consumes these raw)
__device__ __forceinline__ void write_m_split_relu(f32x4* acc, u16* __restrict__ mh,
                                                   u16* __restrict__ ml,
                                                   int p0, int wv, int lane) {
    int q = lane >> 4, l = lane & 15;
    int px = p0 + wv * 16 + l;
#pragma unroll
    for (int ot = 0; ot < 4; ++ot)
#pragma unroll
        for (int j = 0; j < 4; ++j) {
            int o = ot * 16 + q * 4 + j;
            float v = acc[ot][j]; v = v > 0.f ? v : 0.f;
            u16 h, lo2; split_bf(v, h, lo2);
            mh[(size_t)o * NN + px] = h;
            ml[(size_t)o * NN + px] = lo2;
        }
}

__device__ __forceinline__ void write_m_lin(f32x4* acc, float* __restrict__ mout,
                                            int p0, int wv, int lane) {
    int q = lane >> 4, l = lane & 15;
    int px = p0 + wv * 16 + l;
#pragma unroll
    for (int ot = 0; ot < 4; ++ot)
#pragma unroll
        for (int j = 0; j < 4; ++j) {
            int o = ot * 16 + q * 4 + j;
            mout[(size_t)o * NN + px] = acc[ot][j];
        }
}

// ---------------- f1 regular: z(NCHW fp32) -> m1,m2 (split u16 NCHW) ----------------
__global__ __launch_bounds__(256) void f1_reg(
    const float* __restrict__ z,
    const float* __restrict__ W1a, const float* __restrict__ B1a,
    const float* __restrict__ W2a, const float* __restrict__ B2a,
    const float* __restrict__ W1b, const float* __restrict__ B1b,
    const float* __restrict__ W2b, const float* __restrict__ B2b,
    u16* __restrict__ m1h, u16* __restrict__ m1l,
    u16* __restrict__ m2h, u16* __restrict__ m2l) {
    __shared__ u16 zh[64 * TSTR], zl[64 * TSTR];
    __shared__ u16 hh[64 * TSTR], hl[64 * TSTR];
    __shared__ u16 wh[64 * TSTR], wl[64 * TSTR];
    int bb = blockIdx.y, p0 = blockIdx.x * 64;
    int t = threadIdx.x, lane = t & 63, wv = t >> 6;
    size_t gofs = (size_t)bb * EMB * NN;
    const float* zp = z + gofs;

    stage_act_nchw(zp, p0, zh, zl, t);
    stage_w(W1a, 64, 0, wh, wl, t);
    __syncthreads();

    f32x4 acc[4];
    init_bias(B1a, acc, lane);
    layer_half(zh, zl, wh, wl, TSTR, 0, acc, wv, lane);
    write_h(acc, hh, hl, wv, lane);
    __syncthreads();

    stage_w(W2a, 64, 0, wh, wl, t);
    __syncthreads();
    init_bias(B2a, acc, lane);
    layer_half(hh, hl, wh, wl, TSTR, 0, acc, wv, lane);
    write_m_split_relu(acc, m1h + gofs, m1l + gofs, p0, wv, lane);
    __syncthreads();

    stage_w(W1b, 64, 0, wh, wl, t);
    __syncthreads();
    init_bias(B1b, acc, lane);
    layer_half(zh, zl, wh, wl, TSTR, 0, acc, wv, lane);
    write_h(acc, hh, hl, wv, lane);
    __syncthreads();

    stage_w(W2b, 64, 0, wh, wl, t);
    __syncthreads();
    init_bias(B2b, acc, lane);
    layer_half(hh, hl, wh, wl, TSTR, 0, acc, wv, lane);
    write_m_split_relu(acc, m2h + gofs, m2l + gofs, p0, wv, lane);
}

// ---------------- f1 rb0: adj -> m1,m2 (split u16 NCHW) ----------------
__global__ __launch_bounds__(256) void f1_rb0(
    const float* __restrict__ adj, int b_base,
    const float* __restrict__ w1a, const float* __restrict__ b1a,
    const float* __restrict__ W2a, const float* __restrict__ B2a,
    const float* __restrict__ w1b, const float* __restrict__ b1b,
    const float* __restrict__ W2b, const float* __restrict__ B2b,
    u16* __restrict__ m1h, u16* __restrict__ m1l,
    u16* __restrict__ m2h, u16* __restrict__ m2l) {
    __shared__ u16 hh[64 * TSTR], hl[64 * TSTR];
    __shared__ u16 wh[64 * TSTR], wl[64 * TSTR];
    int bb = blockIdx.y, p0 = blockIdx.x * 64;
    int t = threadIdx.x, lane = t & 63, wv = t >> 6;
    size_t gofs = (size_t)bb * EMB * NN;

    int px = t & 63, oc = (t >> 6) * 16;
    float a = adj[(size_t)(b_base + bb) * NN + p0 + px];

#pragma unroll
    for (int k = 0; k < 16; k += 2) {
        int o = oc + k;
        float v0 = w1a[o * 2] * a + b1a[o];           v0 = v0 > 0.f ? v0 : 0.f;
        float v1 = w1a[(o + 1) * 2] * a + b1a[o + 1]; v1 = v1 > 0.f ? v1 : 0.f;
        u16 h0, l0, h1, l1; split_bf(v0, h0, l0); split_bf(v1, h1, l1);
        *(u32t*)&hh[px * TSTR + o] = (u32t)h0 | ((u32t)h1 << 16);
        *(u32t*)&hl[px * TSTR + o] = (u32t)l0 | ((u32t)l1 << 16);
    }
    stage_w(W2a, 64, 0, wh, wl, t);
    __syncthreads();

    f32x4 acc[4];
    init_bias(B2a, acc, lane);
    layer_half(hh, hl, wh, wl, TSTR, 0, acc, wv, lane);
    write_m_split_relu(acc, m1h + gofs, m1l + gofs, p0, wv, lane);
    __syncthreads();

#pragma unroll
    for (int k = 0; k < 16; k += 2) {
        int o = oc + k;
        float v0 = w1b[o * 2] * a + b1b[o];           v0 = v0 > 0.f ? v0 : 0.f;
        float v1 = w1b[(o + 1) * 2] * a + b1b[o + 1]; v1 = v1 > 0.f ? v1 : 0.f;
        u16 h0, l0, h1, l1; split_bf(v0, h0, l0); split_bf(v1, h1, l1);
        *(u32t*)&hh[px * TSTR + o] = (u32t)h0 | ((u32t)h1 << 16);
        *(u32t*)&hl[px * TSTR + o] = (u32t)l0 | ((u32t)l1 << 16);
    }
    stage_w(W2b, 64, 0, wh, wl, t);
    __syncthreads();

    init_bias(B2b, acc, lane);
    layer_half(hh, hl, wh, wl, TSTR, 0, acc, wv, lane);
    write_m_split_relu(acc, m2h + gofs, m2l + gofs, p0, wv, lane);
}

// ---------------- per-channel NxN matmul via 3-term split MFMA ----------------
// C[i][j] = sum_k m1[i][k] * m2[k][j]; pre-split u16 inputs; out NHWC fp32.
// 64x64 C-tile per WG; A staged [i][k], B transpose-staged [j][k];
// granule-16 XOR swizzle: granule G stored at G ^ ((row>>3)&7).
__global__ __launch_bounds__(256) void chanmm_mfma(
    const u16* __restrict__ m1h, const u16* __restrict__ m1l,
    const u16* __restrict__ m2h, const u16* __restrict__ m2l,
    float* __restrict__ outNHWC) {
    __shared__ u16 Ah[64 * TSTR], Al[64 * TSTR];
    __shared__ u16 Bh[64 * TSTR], Bl[64 * TSTR];
    int t = threadIdx.x, lane = t & 63, wv = t >> 6;
    int q = lane >> 4, l15 = lane & 15;
    int tile = blockIdx.x;
    int itile = (tile >> 2) * 64, jtile = (tile & 3) * 64;
    int ch = blockIdx.y, bb = blockIdx.z;
    size_t pb = ((size_t)bb * EMB + ch) * NN;
    const u16* A_h = m1h + pb; const u16* A_l = m1l + pb;
    const u16* B_h = m2h + pb; const u16* B_l = m2l + pb;

    f32x4 acc[4] = {};
    for (int k0 = 0; k0 < N; k0 += 64) {
        if (k0) __syncthreads();
        // ---- A stage: linear [i][k], b128 copies, swizzled granule ----
#pragma unroll
        for (int r = 0; r < 2; ++r) {
            int idx = r * 256 + t;           // i(64) x G(8)
            int ai = idx >> 3, G = idx & 7;
            int src = (itile + ai) * N + k0 + G * 8;
            int dst = ai * TSTR + ((G ^ ((ai >> 3) & 7)) << 3);
            *(int4*)&Ah[dst] = *(const int4*)&A_h[src];
            *(int4*)&Al[dst] = *(const int4*)&A_l[src];
        }
        // ---- B stage: transpose [k][j] -> [j][k], scalar u16 writes, swizzled ----
#pragma unroll
        for (int r = 0; r < 2; ++r) {
            int idx = r * 256 + t;           // k(64) x j8(8)
            int bk = idx >> 3, j8 = (idx & 7) * 8;
            int src = (k0 + bk) * N + jtile + j8;
            int4 vh = *(const int4*)&B_h[src];
            int4 vl = *(const int4*)&B_l[src];
            const u16* ph = (const u16*)&vh;
            const u16* pl = (const u16*)&vl;
            int G = bk >> 3, kin = bk & 7;
#pragma unroll
            for (int d = 0; d < 8; ++d) {
                int j = j8 + d;
                int dst = j * TSTR + ((G ^ ((j >> 3) & 7)) << 3) + kin;
                Bh[dst] = ph[d];
                Bl[dst] = pl[d];
            }
        }
        __syncthreads();
        // ---- MFMA: 2 ks x 4 ot x 3 split terms ----
#pragma unroll
        for (int ks = 0; ks < 2; ++ks) {
            int Gr = ks * 4 + q;
            int j = wv * 16 + l15;
            int boff = j * TSTR + ((Gr ^ ((j >> 3) & 7)) << 3);
            bf16x8 bhi = *(const bf16x8*)&Bh[boff];
            bf16x8 blo = *(const bf16x8*)&Bl[boff];
#pragma unroll
            for (int ot = 0; ot < 4; ++ot) {
                int i = ot * 16 + l15;
                int aoff = i * TSTR + ((Gr ^ ((i >> 3) & 7)) << 3);
                bf16x8 ahi = *(const bf16x8*)&Ah[aoff];
                bf16x8 alo = *(const bf16x8*)&Al[aoff];
                acc[ot] = __builtin_amdgcn_mfma_f32_16x16x32_bf16(ahi, bhi, acc[ot], 0, 0, 0);
                acc[ot] = __builtin_amdgcn_mfma_f32_16x16x32_bf16(ahi, blo, acc[ot], 0, 0, 0);
                acc[ot] = __builtin_amdgcn_mfma_f32_16x16x32_bf16(alo, bhi, acc[ot], 0, 0, 0);
            }
        }
    }
    // ---- write C tile to mult NHWC ----
#pragma unroll
    for (int ot = 0; ot < 4; ++ot)
#pragma unroll
        for (int jj = 0; jj < 4; ++jj) {
            int ig = itile + ot * 16 + q * 4 + jj;
            int jg = jtile + wv * 16 + l15;
            outNHWC[((size_t)bb * NN + (size_t)ig * N + jg) * EMB + ch] = acc[ot][jj];
        }
}

// ---------------- f2 regular: skip conv K=128 over [z || mult] -> z ----------------
__global__ __launch_bounds__(256) void f2_reg(
    const float* __restrict__ mult,
    const float* __restrict__ SW, const float* __restrict__ SB,
    float* __restrict__ z) {
    __shared__ u16 ah[64 * TSTR], al[64 * TSTR];
    __shared__ u16 wh[64 * WSTR2], wl[64 * WSTR2];
    int bb = blockIdx.y, p0 = blockIdx.x * 64;
    int t = threadIdx.x, lane = t & 63, wv = t >> 6;
    const float* mp = mult + (size_t)bb * NN * EMB;
    float* zp = z + (size_t)bb * EMB * NN;

    stage_w128(SW, wh, wl, t);
    stage_act_nchw(zp, p0, ah, al, t);
    __syncthreads();

    f32x4 acc[4];
    init_bias(SB, acc, lane);
    layer_half(ah, al, wh, wl, WSTR2, 0, acc, wv, lane);
    __syncthreads();
    stage_act_nhwc(mp, p0, ah, al, t);
    __syncthreads();
    layer_half(ah, al, wh, wl, WSTR2, 64, acc, wv, lane);
    write_m_lin(acc, zp, p0, wv, lane);
}

// ---------------- f2 rb0 ----------------
__global__ __launch_bounds__(256) void f2_rb0(
    const float* __restrict__ adj, int b_base,
    const float* __restrict__ mult,
    const float* __restrict__ SW, const float* __restrict__ SB,
    float* __restrict__ z) {
    __shared__ u16 ah[64 * TSTR], al[64 * TSTR];
    __shared__ u16 wh[64 * TSTR], wl[64 * TSTR];
    int bb = blockIdx.y, p0 = blockIdx.x * 64;
    int t = threadIdx.x, lane = t & 63, wv = t >> 6;
    const float* mp = mult + (size_t)bb * NN * EMB;
    float* zp = z + (size_t)bb * EMB * NN;

    stage_w(SW, 66, 2, wh, wl, t);
    stage_act_nhwc(mp, p0, ah, al, t);
    __syncthreads();

    int q = lane >> 4, l = lane & 15;
    float a = adj[(size_t)(b_base + bb) * NN + p0 + wv * 16 + l];
    f32x4 acc[4];
#pragma unroll
    for (int ot = 0; ot < 4; ++ot)
#pragma unroll
        for (int j = 0; j < 4; ++j) {
            int o = ot * 16 + q * 4 + j;
            acc[ot][j] = SB[o] + SW[o * 66] * a;
        }
    layer_half(ah, al, wh, wl, TSTR, 0, acc, wv, lane);
    write_m_lin(acc, zp, p0, wv, lane);
}

// ---------------- pooling partials (float4 loads, branch-free diag) ----------------
__global__ void pool(const float* __restrict__ z, float* __restrict__ sums, int b_base) {
    int bb = blockIdx.x;
    int c = blockIdx.y;
    size_t base = ((size_t)bb * EMB + c) * NN;
    const float4* z4 = (const float4*)(z + base);
    int t = threadIdx.x;
    float s = 0.0f;
#pragma unroll 4
    for (int it = 0; it < 64; ++it) {
        float4 v = z4[it * 256 + t];
        s += v.x + v.y + v.z + v.w;
    }
    float d = z[base + (size_t)t * 257];  // diag element t
    for (int off = 32; off > 0; off >>= 1) {
        s += __shfl_down(s, off);
        d += __shfl_down(d, off);
    }
    __shared__ float ls[4], ld[4];
    int wid = t >> 6;
    if ((t & 63) == 0) { ls[wid] = s; ld[wid] = d; }
    __syncthreads();
    if (t == 0) {
        s = ls[0] + ls[1] + ls[2] + ls[3];
        d = ld[0] + ld[1] + ld[2] + ld[3];
        int b = b_base + bb;
        sums[b * EMB + c] = s;
        sums[BATCH * EMB + b * EMB + c] = d;
    }
}

// ---------------- final pooled FC ----------------
__global__ void fc(const float* __restrict__ sums,
                   const float* __restrict__ fcw1, const float* __restrict__ fcb1,
                   const float* __restrict__ fcw2, const float* __restrict__ fcb2,
                   float* __restrict__ out) {
    int b = blockIdx.x;
    __shared__ float h[128];
    __shared__ float hh2[64];
    int t = threadIdx.x;
    if (t < 64) {
        h[t] = sums[BATCH * EMB + b * EMB + t] / (float)N;
    } else {
        int c = t - 64;
        float sall = sums[b * EMB + c];
        float sd = sums[BATCH * EMB + b * EMB + c];
        h[t] = (sall - sd) / (float)(N * (N - 1));
    }
    __syncthreads();
    if (t < 64) {
        float acc = fcb1[t];
        for (int k = 0; k < 128; ++k) acc += fcw1[t * 128 + k] * h[k];
        hh2[t] = acc > 0.0f ? acc : 0.0f;
    }
    __syncthreads();
    if (t == 0) {
        float acc = fcb2[0];
        for (int k = 0; k < 64; ++k) acc += fcw2[k] * hh2[k];
        out[b] = acc;
    }
}

extern "C" void kernel_launch(void* const* d_in, const int* in_sizes, int n_in,
                              void* d_out, int out_size, void* d_ws, size_t ws_size,
                              hipStream_t stream) {
    const int* ei       = (const int*)d_in[0];
    const int* batchv   = (const int*)d_in[1];
    const float* rb0_m1w1 = (const float*)d_in[2];
    const float* rb0_m1b1 = (const float*)d_in[3];
    const float* rb0_m1w2 = (const float*)d_in[4];
    const float* rb0_m1b2 = (const float*)d_in[5];
    const float* rb0_m2w1 = (const float*)d_in[6];
    const float* rb0_m2b1 = (const float*)d_in[7];
    const float* rb0_m2w2 = (const float*)d_in[8];
    const float* rb0_m2b2 = (const float*)d_in[9];
    const float* rb0_sw   = (const float*)d_in[10];
    const float* rb0_sb   = (const float*)d_in[11];
    const float* rb_m1w1  = (const float*)d_in[12];
    const float* rb_m1b1  = (const float*)d_in[13];
    const float* rb_m1w2  = (const float*)d_in[14];
    const float* rb_m1b2  = (const float*)d_in[15];
    const float* rb_m2w1  = (const float*)d_in[16];
    const float* rb_m2b1  = (const float*)d_in[17];
    const float* rb_m2w2  = (const float*)d_in[18];
    const float* rb_m2b2  = (const float*)d_in[19];
    const float* rb_sw    = (const float*)d_in[20];
    const float* rb_sb    = (const float*)d_in[21];
    const float* fcw1     = (const float*)d_in[22];
    const float* fcb1     = (const float*)d_in[23];
    const float* fcw2     = (const float*)d_in[24];
    const float* fcb2     = (const float*)d_in[25];

    // adaptive graphs-per-pass; per-graph footprint identical to round 5 (67 MB)
    const size_t P = (size_t)EMB * NN;               // 4,194,304 elems
    const size_t perGraphBytes = 4ull * P * 2ull + P * 4ull + P * 4ull; // 4 u16 + mult + z
    int g = BATCH;
    while (g > 1) {
        size_t need = 524288ull * 4ull + 4096ull + (size_t)g * perGraphBytes;
        if (need <= ws_size) break;
        g >>= 1;
    }

    char* w = (char*)d_ws;
    float* adj   = (float*)w;  w += 524288ull * 4ull;       // [B][N][N]
    float* sums  = (float*)w;  w += 4096;                   // [2][B][EMB]
    u16* m1h     = (u16*)w;    w += (size_t)g * P * 2ull;   // NCHW split hi
    u16* m1l     = (u16*)w;    w += (size_t)g * P * 2ull;   // NCHW split lo
    u16* m2h     = (u16*)w;    w += (size_t)g * P * 2ull;
    u16* m2l     = (u16*)w;    w += (size_t)g * P * 2ull;
    float* mult  = (float*)w;  w += (size_t)g * P * 4ull;   // NHWC fp32
    float* znchw = (float*)w;  w += (size_t)g * P * 4ull;   // NCHW fp32

    hipMemsetAsync(adj, 0, 524288ull * 4ull, stream);
    scatter_adj<<<NEDGE / 256, 256, 0, stream>>>(ei, batchv, adj);

    for (int b_base = 0; b_base < BATCH; b_base += g) {
        dim3 gridE(NN / 64, g);
        dim3 gridM(16, EMB, g);

        // rb0
        f1_rb0<<<gridE, 256, 0, stream>>>(adj, b_base,
            rb0_m1w1, rb0_m1b1, rb0_m1w2, rb0_m1b2,
            rb0_m2w1, rb0_m2b1, rb0_m2w2, rb0_m2b2, m1h, m1l, m2h, m2l);
        chanmm_mfma<<<gridM, 256, 0, stream>>>(m1h, m1l, m2h, m2l, mult);
        f2_rb0<<<gridE, 256, 0, stream>>>(adj, b_base, mult, rb0_sw, rb0_sb, znchw);

        // 3 regular blocks
        for (int i = 0; i < 3; ++i) {
            f1_reg<<<gridE, 256, 0, stream>>>(znchw,
                rb_m1w1 + (size_t)i * 4096, rb_m1b1 + i * 64,
                rb_m1w2 + (size_t)i * 4096, rb_m1b2 + i * 64,
                rb_m2w1 + (size_t)i * 4096, rb_m2b1 + i * 64,
                rb_m2w2 + (size_t)i * 4096, rb_m2b2 + i * 64, m1h, m1l, m2h, m2l);
            chanmm_mfma<<<gridM, 256, 0, stream>>>(m1h, m1l, m2h, m2l, mult);
            f2_reg<<<gridE, 256, 0, stream>>>(mult, rb_sw + (size_t)i * 8192, rb_sb + i * 64, znchw);
        }

        pool<<<dim3(g, EMB), 256, 0, stream>>>(znchw, sums, b_base);
    }
    fc<<<BATCH, 128, 0, stream>>>(sums, fcw1, fcb1, fcw2, fcb2, (float*)d_out);
}

// Round 7
// 1503.484 us; speedup vs baseline: 3.9593x; 1.2500x over previous
//
#include <hip/hip_runtime.h>

#define N 256
#define NN 65536
#define EMB 64
#define BATCH 8
#define NEDGE 32768

typedef unsigned short u16;
typedef unsigned int u32t;
typedef __attribute__((ext_vector_type(8))) short bf16x8;
typedef __attribute__((ext_vector_type(4))) float f32x4;

#define TSTR 72    // engine LDS tile row stride in u16 (144 B)
#define WSTR2 136  // K=128 weight tile row stride in u16 (272 B)

static __device__ __forceinline__ u16 f2bs(float f) {
    u32t u = __float_as_uint(f);
    u32t r = (u + 0x7FFFu + ((u >> 16) & 1u)) >> 16;
    return (u16)r;
}
static __device__ __forceinline__ float b2f(u16 s) {
    return __uint_as_float(((u32t)s) << 16);
}
// split fp32 into bf16 hi + bf16 lo (a ~= hi + lo)
static __device__ __forceinline__ void split_bf(float a, u16& hi, u16& lo) {
    hi = f2bs(a);
    float r = a - b2f(hi);
    lo = f2bs(r);
}

// ---------------- adjacency scatter ----------------
__global__ void scatter_adj(const int* __restrict__ ei, const int* __restrict__ batch,
                            float* __restrict__ adj) {
    int e = blockIdx.x * blockDim.x + threadIdx.x;
    if (e >= NEDGE) return;
    int src = ei[e];
    int dst = ei[NEDGE + e];
    int g = batch[src];
    int lu = src - g * N;
    int lv = dst - g * N;
    atomicAdd(&adj[(size_t)g * NN + (size_t)lu * N + lv], 1.0f);
}

// ================= split-MFMA engine helpers (f1/f2) =================

__device__ __forceinline__ void stage_w(const float* __restrict__ W, int ldw, int cofs,
                                        u16* wh, u16* wl, int t) {
#pragma unroll
    for (int it = 0; it < 8; ++it) {
        int idx = it * 256 + t;
        int o = idx >> 5;
        int c0 = (idx & 31) * 2;
        float v0 = W[o * ldw + cofs + c0];
        float v1 = W[o * ldw + cofs + c0 + 1];
        u16 h0, l0, h1, l1;
        split_bf(v0, h0, l0); split_bf(v1, h1, l1);
        *(u32t*)&wh[o * TSTR + c0] = (u32t)h0 | ((u32t)h1 << 16);
        *(u32t*)&wl[o * TSTR + c0] = (u32t)l0 | ((u32t)l1 << 16);
    }
}

__device__ __forceinline__ void stage_w128(const float* __restrict__ W,
                                           u16* wh, u16* wl, int t) {
#pragma unroll
    for (int it = 0; it < 16; ++it) {
        int idx = it * 256 + t;
        int o = idx >> 6;
        int c0 = (idx & 63) * 2;
        float v0 = W[o * 128 + c0];
        float v1 = W[o * 128 + c0 + 1];
        u16 h0, l0, h1, l1;
        split_bf(v0, h0, l0); split_bf(v1, h1, l1);
        *(u32t*)&wh[o * WSTR2 + c0] = (u32t)h0 | ((u32t)h1 << 16);
        *(u32t*)&wl[o * WSTR2 + c0] = (u32t)l0 | ((u32t)l1 << 16);
    }
}

__device__ __forceinline__ void stage_act_nchw(const float* __restrict__ src, int p0,
                                               u16* ah, u16* al, int t) {
#pragma unroll
    for (int it = 0; it < 8; ++it) {
        int idx = it * 256 + t;
        int px = idx & 63;
        int c0 = (idx >> 6) * 2;
        float v0 = src[(size_t)c0 * NN + p0 + px];
        float v1 = src[(size_t)(c0 + 1) * NN + p0 + px];
        u16 h0, l0, h1, l1;
        split_bf(v0, h0, l0); split_bf(v1, h1, l1);
        *(u32t*)&ah[px * TSTR + c0] = (u32t)h0 | ((u32t)h1 << 16);
        *(u32t*)&al[px * TSTR + c0] = (u32t)l0 | ((u32t)l1 << 16);
    }
}

__device__ __forceinline__ void init_bias(const float* __restrict__ Bb, f32x4* acc, int lane) {
    int q = lane >> 4;
#pragma unroll
    for (int ot = 0; ot < 4; ++ot)
#pragma unroll
        for (int j = 0; j < 4; ++j)
            acc[ot][j] = Bb[ot * 16 + q * 4 + j];
}

__device__ __forceinline__ void layer_half(const u16* bh, const u16* bl,
                                           const u16* wh, const u16* wl,
                                           int wstr, int ak0,
                                           f32x4* acc, int wv, int lane) {
    int q = lane >> 4, l = lane & 15;
#pragma unroll
    for (int ks = 0; ks < 2; ++ks) {
        int boff = (wv * 16 + l) * TSTR + ks * 32 + q * 8;
        bf16x8 bhi = *(const bf16x8*)&bh[boff];
        bf16x8 blo = *(const bf16x8*)&bl[boff];
#pragma unroll
        for (int ot = 0; ot < 4; ++ot) {
            int aoff = (ot * 16 + l) * wstr + ak0 + ks * 32 + q * 8;
            bf16x8 ahi = *(const bf16x8*)&wh[aoff];
            bf16x8 alo = *(const bf16x8*)&wl[aoff];
            acc[ot] = __builtin_amdgcn_mfma_f32_16x16x32_bf16(ahi, bhi, acc[ot], 0, 0, 0);
            acc[ot] = __builtin_amdgcn_mfma_f32_16x16x32_bf16(ahi, blo, acc[ot], 0, 0, 0);
            acc[ot] = __builtin_amdgcn_mfma_f32_16x16x32_bf16(alo, bhi, acc[ot], 0, 0, 0);
        }
    }
}

__device__ __forceinline__ void write_h(f32x4* acc, u16* hh, u16* hl, int wv, int lane) {
    int q = lane >> 4, l = lane & 15;
    int px = wv * 16 + l;
#pragma unroll
    for (int ot = 0; ot < 4; ++ot) {
#pragma unroll
        for (int jp = 0; jp < 2; ++jp) {
            int o = ot * 16 + q * 4 + jp * 2;
            float v0 = acc[ot][jp * 2];     v0 = v0 > 0.f ? v0 : 0.f;
            float v1 = acc[ot][jp * 2 + 1]; v1 = v1 > 0.f ? v1 : 0.f;
            u16 h0, l0, h1, l1;
            split_bf(v0, h0, l0); split_bf(v1, h1, l1);
            *(u32t*)&hh[px * TSTR + o] = (u32t)h0 | ((u32t)h1 << 16);
            *(u32t*)&hl[px * TSTR + o] = (u32t)l0 | ((u32t)l1 << 16);
        }
    }
}

// write relu(acc) pre-split to hi/lo u16 NCHW planes (chanmm consumes these raw)
__device__ __forceinline__ void write_m_split_relu(f32x4* acc, u16* __restrict__ mh,
                                                   u16* __restrict__ ml,
                                                   int p0, int wv, int lane) {
    int q = lane >> 4, l = lane & 15;
    int px = p0 + wv * 16 + l;
#pragma unroll
    for (int ot = 0; ot < 4; ++ot)
#pragma unroll
        for (int j = 0; j < 4; ++j) {
            int o = ot * 16 + q * 4 + j;
            float v = acc[ot][j]; v = v > 0.f ? v : 0.f;
            u16 h, lo2; split_bf(v, h, lo2);
            mh[(size_t)o * NN + px] = h;
            ml[(size_t)o * NN + px] = lo2;
        }
}

__device__ __forceinline__ void write_m_lin(f32x4* acc, float* __restrict__ mout,
                                            int p0, int wv, int lane) {
    int q = lane >> 4, l = lane & 15;
    int px = p0 + wv * 16 + l;
#pragma unroll
    for (int ot = 0; ot < 4; ++ot)
#pragma unroll
        for (int j = 0; j < 4; ++j) {
            int o = ot * 16 + q * 4 + j;
            mout[(size_t)o * NN + px] = acc[ot][j];
        }
}

// ---------------- f1 regular: z(NCHW fp32) -> m1,m2 (split u16 NCHW) ----------------
__global__ __launch_bounds__(256) void f1_reg(
    const float* __restrict__ z,
    const float* __restrict__ W1a, const float* __restrict__ B1a,
    const float* __restrict__ W2a, const float* __restrict__ B2a,
    const float* __restrict__ W1b, const float* __restrict__ B1b,
    const float* __restrict__ W2b, const float* __restrict__ B2b,
    u16* __restrict__ m1h, u16* __restrict__ m1l,
    u16* __restrict__ m2h, u16* __restrict__ m2l) {
    __shared__ u16 zh[64 * TSTR], zl[64 * TSTR];
    __shared__ u16 hh[64 * TSTR], hl[64 * TSTR];
    __shared__ u16 wh[64 * TSTR], wl[64 * TSTR];
    int bb = blockIdx.y, p0 = blockIdx.x * 64;
    int t = threadIdx.x, lane = t & 63, wv = t >> 6;
    size_t gofs = (size_t)bb * EMB * NN;
    const float* zp = z + gofs;

    stage_act_nchw(zp, p0, zh, zl, t);
    stage_w(W1a, 64, 0, wh, wl, t);
    __syncthreads();

    f32x4 acc[4];
    init_bias(B1a, acc, lane);
    layer_half(zh, zl, wh, wl, TSTR, 0, acc, wv, lane);
    write_h(acc, hh, hl, wv, lane);
    __syncthreads();

    stage_w(W2a, 64, 0, wh, wl, t);
    __syncthreads();
    init_bias(B2a, acc, lane);
    layer_half(hh, hl, wh, wl, TSTR, 0, acc, wv, lane);
    write_m_split_relu(acc, m1h + gofs, m1l + gofs, p0, wv, lane);
    __syncthreads();

    stage_w(W1b, 64, 0, wh, wl, t);
    __syncthreads();
    init_bias(B1b, acc, lane);
    layer_half(zh, zl, wh, wl, TSTR, 0, acc, wv, lane);
    write_h(acc, hh, hl, wv, lane);
    __syncthreads();

    stage_w(W2b, 64, 0, wh, wl, t);
    __syncthreads();
    init_bias(B2b, acc, lane);
    layer_half(hh, hl, wh, wl, TSTR, 0, acc, wv, lane);
    write_m_split_relu(acc, m2h + gofs, m2l + gofs, p0, wv, lane);
}

// ---------------- f1 rb0: adj -> m1,m2 (split u16 NCHW) ----------------
__global__ __launch_bounds__(256) void f1_rb0(
    const float* __restrict__ adj, int b_base,
    const float* __restrict__ w1a, const float* __restrict__ b1a,
    const float* __restrict__ W2a, const float* __restrict__ B2a,
    const float* __restrict__ w1b, const float* __restrict__ b1b,
    const float* __restrict__ W2b, const float* __restrict__ B2b,
    u16* __restrict__ m1h, u16* __restrict__ m1l,
    u16* __restrict__ m2h, u16* __restrict__ m2l) {
    __shared__ u16 hh[64 * TSTR], hl[64 * TSTR];
    __shared__ u16 wh[64 * TSTR], wl[64 * TSTR];
    int bb = blockIdx.y, p0 = blockIdx.x * 64;
    int t = threadIdx.x, lane = t & 63, wv = t >> 6;
    size_t gofs = (size_t)bb * EMB * NN;

    int px = t & 63, oc = (t >> 6) * 16;
    float a = adj[(size_t)(b_base + bb) * NN + p0 + px];

#pragma unroll
    for (int k = 0; k < 16; k += 2) {
        int o = oc + k;
        float v0 = w1a[o * 2] * a + b1a[o];           v0 = v0 > 0.f ? v0 : 0.f;
        float v1 = w1a[(o + 1) * 2] * a + b1a[o + 1]; v1 = v1 > 0.f ? v1 : 0.f;
        u16 h0, l0, h1, l1; split_bf(v0, h0, l0); split_bf(v1, h1, l1);
        *(u32t*)&hh[px * TSTR + o] = (u32t)h0 | ((u32t)h1 << 16);
        *(u32t*)&hl[px * TSTR + o] = (u32t)l0 | ((u32t)l1 << 16);
    }
    stage_w(W2a, 64, 0, wh, wl, t);
    __syncthreads();

    f32x4 acc[4];
    init_bias(B2a, acc, lane);
    layer_half(hh, hl, wh, wl, TSTR, 0, acc, wv, lane);
    write_m_split_relu(acc, m1h + gofs, m1l + gofs, p0, wv, lane);
    __syncthreads();

#pragma unroll
    for (int k = 0; k < 16; k += 2) {
        int o = oc + k;
        float v0 = w1b[o * 2] * a + b1b[o];           v0 = v0 > 0.f ? v0 : 0.f;
        float v1 = w1b[(o + 1) * 2] * a + b1b[o + 1]; v1 = v1 > 0.f ? v1 : 0.f;
        u16 h0, l0, h1, l1; split_bf(v0, h0, l0); split_bf(v1, h1, l1);
        *(u32t*)&hh[px * TSTR + o] = (u32t)h0 | ((u32t)h1 << 16);
        *(u32t*)&hl[px * TSTR + o] = (u32t)l0 | ((u32t)l1 << 16);
    }
    stage_w(W2b, 64, 0, wh, wl, t);
    __syncthreads();

    init_bias(B2b, acc, lane);
    layer_half(hh, hl, wh, wl, TSTR, 0, acc, wv, lane);
    write_m_split_relu(acc, m2h + gofs, m2l + gofs, p0, wv, lane);
}

// ---------------- per-channel NxN matmul via 3-term split MFMA (v3) ----------------
// 512 threads, 8 waves; C-tile 128(i) x 64(j); K-steps of 64 with reg-prefetch.
// LDS rows linear [row][64] u16 with granule swizzle g ^= (row&7) ^ ((row>>3)&7).
// mult written NCHW fp32 (coalesced).
__device__ __forceinline__ int soff(int row, int g) {
    return row * 64 + ((g ^ (row & 7) ^ ((row >> 3) & 7)) << 3);
}

__global__ __launch_bounds__(512) void chanmm_mfma(
    const u16* __restrict__ m1h, const u16* __restrict__ m1l,
    const u16* __restrict__ m2h, const u16* __restrict__ m2l,
    float* __restrict__ mult) {
    __shared__ u16 Ah[128 * 64], Al[128 * 64];   // 16 KB each
    __shared__ u16 Bh[64 * 64],  Bl[64 * 64];    // 8 KB each -> 48 KB total
    int t = threadIdx.x, lane = t & 63, wv = t >> 6;
    int l15 = lane & 15, q = lane >> 4;
    int wi = wv >> 1, wj = wv & 1;               // 4 x 2 wave grid (32i x 32j each)
    int tile = blockIdx.x;
    int itile = (tile >> 2) * 128, jtile = (tile & 3) * 64;
    int ch = blockIdx.y, bb = blockIdx.z;
    size_t pb = ((size_t)bb * EMB + ch) * NN;
    const u16* A_h = m1h + pb; const u16* A_l = m1l + pb;
    const u16* B_h = m2h + pb; const u16* B_l = m2l + pb;

    // per-thread staging coords
    int a_i = t >> 3;            // 0..63 (second iter: +64)
    int a_g = t & 7;
    int b_k = t >> 3;            // 0..63
    int b_j8 = (t & 7) * 8;

    int4 rAh0, rAl0, rAh1, rAl1, rBh, rBl;
#define LOADK(K0)                                                              \
    {                                                                          \
        int k0_ = (K0);                                                        \
        rAh0 = *(const int4*)&A_h[(itile + a_i) * N + k0_ + a_g * 8];          \
        rAl0 = *(const int4*)&A_l[(itile + a_i) * N + k0_ + a_g * 8];          \
        rAh1 = *(const int4*)&A_h[(itile + 64 + a_i) * N + k0_ + a_g * 8];     \
        rAl1 = *(const int4*)&A_l[(itile + 64 + a_i) * N + k0_ + a_g * 8];     \
        rBh  = *(const int4*)&B_h[(k0_ + b_k) * N + jtile + b_j8];             \
        rBl  = *(const int4*)&B_l[(k0_ + b_k) * N + jtile + b_j8];             \
    }

    f32x4 acc[2][2] = {};
    LOADK(0);
#pragma unroll
    for (int s = 0; s < 4; ++s) {
        // ---- write staged regs to LDS ----
        *(int4*)&Ah[soff(a_i, a_g)] = rAh0;
        *(int4*)&Al[soff(a_i, a_g)] = rAl0;
        *(int4*)&Ah[soff(a_i + 64, a_g)] = rAh1;
        *(int4*)&Al[soff(a_i + 64, a_g)] = rAl1;
        {
            const u16* ph = (const u16*)&rBh;
            const u16* pl = (const u16*)&rBl;
            int G = b_k >> 3, kin = b_k & 7;
#pragma unroll
            for (int d = 0; d < 8; ++d) {
                int j = b_j8 + d;
                Bh[soff(j, G) + kin] = ph[d];
                Bl[soff(j, G) + kin] = pl[d];
            }
        }
        __syncthreads();
        if (s < 3) LOADK((s + 1) * 64);   // prefetch next K-step (lands during MFMA)
        // ---- MFMA phase ----
#pragma unroll
        for (int ks = 0; ks < 2; ++ks) {
            int g = ks * 4 + q;
            bf16x8 bhi[2], blo[2];
#pragma unroll
            for (int jt = 0; jt < 2; ++jt) {
                int rj = wj * 32 + jt * 16 + l15;
                int o = soff(rj, g);
                bhi[jt] = *(const bf16x8*)&Bh[o];
                blo[jt] = *(const bf16x8*)&Bl[o];
            }
#pragma unroll
            for (int it = 0; it < 2; ++it) {
                int ri = wi * 32 + it * 16 + l15;
                int o = soff(ri, g);
                bf16x8 ahi = *(const bf16x8*)&Ah[o];
                bf16x8 alo = *(const bf16x8*)&Al[o];
#pragma unroll
                for (int jt = 0; jt < 2; ++jt) {
                    acc[it][jt] = __builtin_amdgcn_mfma_f32_16x16x32_bf16(ahi, bhi[jt], acc[it][jt], 0, 0, 0);
                    acc[it][jt] = __builtin_amdgcn_mfma_f32_16x16x32_bf16(ahi, blo[jt], acc[it][jt], 0, 0, 0);
                    acc[it][jt] = __builtin_amdgcn_mfma_f32_16x16x32_bf16(alo, bhi[jt], acc[it][jt], 0, 0, 0);
                }
            }
        }
        __syncthreads();
    }
#undef LOADK
    // ---- epilogue: write C tile NCHW fp32 (coalesced) ----
    float* O = mult + pb;
#pragma unroll
    for (int it = 0; it < 2; ++it)
#pragma unroll
        for (int jt = 0; jt < 2; ++jt)
#pragma unroll
            for (int r = 0; r < 4; ++r) {
                int i = itile + wi * 32 + it * 16 + q * 4 + r;
                int j = jtile + wj * 32 + jt * 16 + l15;
                O[(size_t)i * N + j] = acc[it][jt][r];
            }
}

// ---------------- f2 regular: skip conv K=128 over [z || mult] -> z ----------------
__global__ __launch_bounds__(256) void f2_reg(
    const float* __restrict__ mult,   // NCHW fp32
    const float* __restrict__ SW, const float* __restrict__ SB,
    float* __restrict__ z) {
    __shared__ u16 ah[64 * TSTR], al[64 * TSTR];
    __shared__ u16 wh[64 * WSTR2], wl[64 * WSTR2];
    int bb = blockIdx.y, p0 = blockIdx.x * 64;
    int t = threadIdx.x, lane = t & 63, wv = t >> 6;
    const float* mp = mult + (size_t)bb * EMB * NN;
    float* zp = z + (size_t)bb * EMB * NN;

    stage_w128(SW, wh, wl, t);
    stage_act_nchw(zp, p0, ah, al, t);
    __syncthreads();

    f32x4 acc[4];
    init_bias(SB, acc, lane);
    layer_half(ah, al, wh, wl, WSTR2, 0, acc, wv, lane);
    __syncthreads();
    stage_act_nchw(mp, p0, ah, al, t);
    __syncthreads();
    layer_half(ah, al, wh, wl, WSTR2, 64, acc, wv, lane);
    write_m_lin(acc, zp, p0, wv, lane);
}

// ---------------- f2 rb0 ----------------
__global__ __launch_bounds__(256) void f2_rb0(
    const float* __restrict__ adj, int b_base,
    const float* __restrict__ mult,   // NCHW fp32
    const float* __restrict__ SW, const float* __restrict__ SB,
    float* __restrict__ z) {
    __shared__ u16 ah[64 * TSTR], al[64 * TSTR];
    __shared__ u16 wh[64 * TSTR], wl[64 * TSTR];
    int bb = blockIdx.y, p0 = blockIdx.x * 64;
    int t = threadIdx.x, lane = t & 63, wv = t >> 6;
    const float* mp = mult + (size_t)bb * EMB * NN;
    float* zp = z + (size_t)bb * EMB * NN;

    stage_w(SW, 66, 2, wh, wl, t);
    stage_act_nchw(mp, p0, ah, al, t);
    __syncthreads();

    int q = lane >> 4, l = lane & 15;
    float a = adj[(size_t)(b_base + bb) * NN + p0 + wv * 16 + l];
    f32x4 acc[4];
#pragma unroll
    for (int ot = 0; ot < 4; ++ot)
#pragma unroll
        for (int j = 0; j < 4; ++j) {
            int o = ot * 16 + q * 4 + j;
            acc[ot][j] = SB[o] + SW[o * 66] * a;
        }
    layer_half(ah, al, wh, wl, TSTR, 0, acc, wv, lane);
    write_m_lin(acc, zp, p0, wv, lane);
}

// ---------------- pooling partials (float4 loads, branch-free diag) ----------------
__global__ void pool(const float* __restrict__ z, float* __restrict__ sums, int b_base) {
    int bb = blockIdx.x;
    int c = blockIdx.y;
    size_t base = ((size_t)bb * EMB + c) * NN;
    const float4* z4 = (const float4*)(z + base);
    int t = threadIdx.x;
    float s = 0.0f;
#pragma unroll 4
    for (int it = 0; it < 64; ++it) {
        float4 v = z4[it * 256 + t];
        s += v.x + v.y + v.z + v.w;
    }
    float d = z[base + (size_t)t * 257];  // diag element t
    for (int off = 32; off > 0; off >>= 1) {
        s += __shfl_down(s, off);
        d += __shfl_down(d, off);
    }
    __shared__ float ls[4], ld[4];
    int wid = t >> 6;
    if ((t & 63) == 0) { ls[wid] = s; ld[wid] = d; }
    __syncthreads();
    if (t == 0) {
        s = ls[0] + ls[1] + ls[2] + ls[3];
        d = ld[0] + ld[1] + ld[2] + ld[3];
        int b = b_base + bb;
        sums[b * EMB + c] = s;
        sums[BATCH * EMB + b * EMB + c] = d;
    }
}

// ---------------- final pooled FC ----------------
__global__ void fc(const float* __restrict__ sums,
                   const float* __restrict__ fcw1, const float* __restrict__ fcb1,
                   const float* __restrict__ fcw2, const float* __restrict__ fcb2,
                   float* __restrict__ out) {
    int b = blockIdx.x;
    __shared__ float h[128];
    __shared__ float hh2[64];
    int t = threadIdx.x;
    if (t < 64) {
        h[t] = sums[BATCH * EMB + b * EMB + t] / (float)N;
    } else {
        int c = t - 64;
        float sall = sums[b * EMB + c];
        float sd = sums[BATCH * EMB + b * EMB + c];
        h[t] = (sall - sd) / (float)(N * (N - 1));
    }
    __syncthreads();
    if (t < 64) {
        float acc = fcb1[t];
        for (int k = 0; k < 128; ++k) acc += fcw1[t * 128 + k] * h[k];
        hh2[t] = acc > 0.0f ? acc : 0.0f;
    }
    __syncthreads();
    if (t == 0) {
        float acc = fcb2[0];
        for (int k = 0; k < 64; ++k) acc += fcw2[k] * hh2[k];
        out[b] = acc;
    }
}

extern "C" void kernel_launch(void* const* d_in, const int* in_sizes, int n_in,
                              void* d_out, int out_size, void* d_ws, size_t ws_size,
                              hipStream_t stream) {
    const int* ei       = (const int*)d_in[0];
    const int* batchv   = (const int*)d_in[1];
    const float* rb0_m1w1 = (const float*)d_in[2];
    const float* rb0_m1b1 = (const float*)d_in[3];
    const float* rb0_m1w2 = (const float*)d_in[4];
    const float* rb0_m1b2 = (const float*)d_in[5];
    const float* rb0_m2w1 = (const float*)d_in[6];
    const float* rb0_m2b1 = (const float*)d_in[7];
    const float* rb0_m2w2 = (const float*)d_in[8];
    const float* rb0_m2b2 = (const float*)d_in[9];
    const float* rb0_sw   = (const float*)d_in[10];
    const float* rb0_sb   = (const float*)d_in[11];
    const float* rb_m1w1  = (const float*)d_in[12];
    const float* rb_m1b1  = (const float*)d_in[13];
    const float* rb_m1w2  = (const float*)d_in[14];
    const float* rb_m1b2  = (const float*)d_in[15];
    const float* rb_m2w1  = (const float*)d_in[16];
    const float* rb_m2b1  = (const float*)d_in[17];
    const float* rb_m2w2  = (const float*)d_in[18];
    const float* rb_m2b2  = (const float*)d_in[19];
    const float* rb_sw    = (const float*)d_in[20];
    const float* rb_sb    = (const float*)d_in[21];
    const float* fcw1     = (const float*)d_in[22];
    const float* fcb1     = (const float*)d_in[23];
    const float* fcw2     = (const float*)d_in[24];
    const float* fcb2     = (const float*)d_in[25];

    // adaptive graphs-per-pass; per-graph footprint 67 MB
    const size_t P = (size_t)EMB * NN;               // 4,194,304 elems
    const size_t perGraphBytes = 4ull * P * 2ull + P * 4ull + P * 4ull; // 4 u16 + mult + z
    int g = BATCH;
    while (g > 1) {
        size_t need = 524288ull * 4ull + 4096ull + (size_t)g * perGraphBytes;
        if (need <= ws_size) break;
        g >>= 1;
    }

    char* w = (char*)d_ws;
    float* adj   = (float*)w;  w += 524288ull * 4ull;       // [B][N][N]
    float* sums  = (float*)w;  w += 4096;                   // [2][B][EMB]
    u16* m1h     = (u16*)w;    w += (size_t)g * P * 2ull;   // NCHW split hi
    u16* m1l     = (u16*)w;    w += (size_t)g * P * 2ull;   // NCHW split lo
    u16* m2h     = (u16*)w;    w += (size_t)g * P * 2ull;
    u16* m2l     = (u16*)w;    w += (size_t)g * P * 2ull;
    float* mult  = (float*)w;  w += (size_t)g * P * 4ull;   // NCHW fp32
    float* znchw = (float*)w;  w += (size_t)g * P * 4ull;   // NCHW fp32

    hipMemsetAsync(adj, 0, 524288ull * 4ull, stream);
    scatter_adj<<<NEDGE / 256, 256, 0, stream>>>(ei, batchv, adj);

    for (int b_base = 0; b_base < BATCH; b_base += g) {
        dim3 gridE(NN / 64, g);
        dim3 gridM(8, EMB, g);   // 2 itile x 4 jtile

        // rb0
        f1_rb0<<<gridE, 256, 0, stream>>>(adj, b_base,
            rb0_m1w1, rb0_m1b1, rb0_m1w2, rb0_m1b2,
            rb0_m2w1, rb0_m2b1, rb0_m2w2, rb0_m2b2, m1h, m1l, m2h, m2l);
        chanmm_mfma<<<gridM, 512, 0, stream>>>(m1h, m1l, m2h, m2l, mult);
        f2_rb0<<<gridE, 256, 0, stream>>>(adj, b_base, mult, rb0_sw, rb0_sb, znchw);

        // 3 regular blocks
        for (int i = 0; i < 3; ++i) {
            f1_reg<<<gridE, 256, 0, stream>>>(znchw,
                rb_m1w1 + (size_t)i * 4096, rb_m1b1 + i * 64,
                rb_m1w2 + (size_t)i * 4096, rb_m1b2 + i * 64,
                rb_m2w1 + (size_t)i * 4096, rb_m2b1 + i * 64,
                rb_m2w2 + (size_t)i * 4096, rb_m2b2 + i * 64, m1h, m1l, m2h, m2l);
            chanmm_mfma<<<gridM, 512, 0, stream>>>(m1h, m1l, m2h, m2l, mult);
            f2_reg<<<gridE, 256, 0, stream>>>(mult, rb_sw + (size_t)i * 8192, rb_sb + i * 64, znchw);
        }

        pool<<<dim3(g, EMB), 256, 0, stream>>>(znchw, sums, b_base);
    }
    fc<<<BATCH, 128, 0, stream>>>(sums, fcw1, fcb1, fcw2, fcb2, (float*)d_out);
}